// Round 2
// baseline (1879.424 us; speedup 1.0000x reference)
//
#include <hip/hip_runtime.h>

#define N_USERS 100000
#define N_ITEMS 50000
#define N_NODES 150000
#define NNZ_C   6000000
#define LAT     64
#define BATCH   2048

#define BROWS   128                                  // rows per bucket
#define NBUCK   ((N_NODES + BROWS - 1) / BROWS)      // 1172

// ---------------- utility ----------------
__global__ __launch_bounds__(256) void k_zero(int* p, int n) {
    int i = blockIdx.x * blockDim.x + threadIdx.x;
    if (i < n) p[i] = 0;
}

// ---------------- bucket histogram (LDS sub-hist) ----------------
__global__ __launch_bounds__(256) void k_bucket_hist(const int* __restrict__ row,
                                                     int* __restrict__ gcnt) {
    __shared__ int h[NBUCK];
    for (int k = threadIdx.x; k < NBUCK; k += 256) h[k] = 0;
    __syncthreads();
    int i = blockIdx.x * blockDim.x + threadIdx.x;
    int stride = gridDim.x * blockDim.x;
    for (; i < NNZ_C; i += stride) atomicAdd(&h[row[i] >> 7], 1);
    __syncthreads();
    for (int k = threadIdx.x; k < NBUCK; k += 256) {
        int v = h[k];
        if (v) atomicAdd(&gcnt[k], v);
    }
}

// single block: exclusive scan of bucket counts -> base, cursor; total -> row_ptr[N_NODES]
__global__ __launch_bounds__(256) void k_bucket_scan(const int* __restrict__ cnt,
                                                     int* __restrict__ base,
                                                     int* __restrict__ cursor,
                                                     int* __restrict__ row_ptr) {
    __shared__ int s[256];
    __shared__ int carry;
    int t = threadIdx.x;
    if (t == 0) carry = 0;
    __syncthreads();
    for (int c0 = 0; c0 < NBUCK; c0 += 256) {
        int idx = c0 + t;
        int v = (idx < NBUCK) ? cnt[idx] : 0;
        s[t] = v; __syncthreads();
        for (int off = 1; off < 256; off <<= 1) {
            int x = (t >= off) ? s[t - off] : 0;
            __syncthreads();
            s[t] += x;
            __syncthreads();
        }
        int excl = carry + s[t] - v;
        if (idx < NBUCK) { base[idx] = excl; cursor[idx] = excl; }
        __syncthreads();
        if (t == 255) carry += s[255];
        __syncthreads();
    }
    if (t == 0) { base[NBUCK] = carry; row_ptr[N_NODES] = carry; }
}

// ---------------- phase 1: scatter into bucket regions (streaming frontiers) ----------------
__global__ __launch_bounds__(256) void k_scatter1(const int* __restrict__ row,
                                                  const int* __restrict__ col,
                                                  const float* __restrict__ vals,
                                                  int* cursor, int2* __restrict__ tmp, int n) {
    int i = blockIdx.x * blockDim.x + threadIdx.x;
    int stride = gridDim.x * blockDim.x;
    for (; i < n; i += stride) {
        int r = row[i];
        int b = r >> 7;
        int pos = atomicAdd(&cursor[b], 1);
        tmp[pos] = make_int2(((r & 127) << 24) | col[i], __float_as_int(vals[i]));
    }
}

// ---------------- phase 2: per-bucket local counting sort -> final CSR ----------------
__global__ __launch_bounds__(256) void k_scatter2(const int* __restrict__ base,
                                                  const int2* __restrict__ tmp,
                                                  int2* __restrict__ edges,
                                                  int* __restrict__ row_ptr) {
    __shared__ int cnt[BROWS];
    __shared__ int s[BROWS];
    __shared__ int cur[BROWS];
    int b = blockIdx.x, t = threadIdx.x;
    int beg = base[b], end = base[b + 1];
    if (t < BROWS) cnt[t] = 0;
    __syncthreads();
    for (int i = beg + t; i < end; i += 256)
        atomicAdd(&cnt[tmp[i].x >> 24], 1);
    __syncthreads();
    if (t < BROWS) s[t] = cnt[t];
    __syncthreads();
    for (int off = 1; off < BROWS; off <<= 1) {
        int x = (t >= off && t < BROWS) ? s[t - off] : 0;
        __syncthreads();
        if (t < BROWS) s[t] += x;
        __syncthreads();
    }
    if (t < BROWS) {
        int excl = beg + s[t] - cnt[t];
        cur[t] = excl;
        int g = b * BROWS + t;
        if (g < N_NODES) row_ptr[g] = excl;
    }
    __syncthreads();
    for (int i = beg + t; i < end; i += 256) {
        int2 e = tmp[i];
        int pos = atomicAdd(&cur[e.x >> 24], 1);
        edges[pos] = make_int2(e.x & 0xFFFFFF, e.y);
    }
}

// ---------------- SpMM: wave per row, lane = latent dim ----------------
template <bool SPLIT>
__global__ __launch_bounds__(256) void k_spmm(const int* __restrict__ row_ptr,
                                              const int2* __restrict__ edges,
                                              const float* __restrict__ x0,
                                              const float* __restrict__ x1,
                                              float* __restrict__ y) {
    int wv = (int)((blockIdx.x * blockDim.x + threadIdx.x) >> 6);
    int wave = __builtin_amdgcn_readfirstlane(wv);
    int lane = threadIdx.x & 63;
    if (wave >= N_NODES) return;
    int beg = row_ptr[wave], end = row_ptr[wave + 1];
    float a0 = 0.f, a1 = 0.f, a2 = 0.f, a3 = 0.f;
    auto xrow = [&](int c) -> const float* {
        if (SPLIT)
            return (c < N_USERS) ? x0 + ((size_t)c << 6)
                                 : x1 + ((size_t)(c - N_USERS) << 6);
        return x0 + ((size_t)c << 6);
    };
    int j = beg;
    for (; j + 4 <= end; j += 4) {
        int2 e0 = edges[j], e1 = edges[j + 1], e2 = edges[j + 2], e3 = edges[j + 3];
        a0 += __int_as_float(e0.y) * xrow(e0.x)[lane];
        a1 += __int_as_float(e1.y) * xrow(e1.x)[lane];
        a2 += __int_as_float(e2.y) * xrow(e2.x)[lane];
        a3 += __int_as_float(e3.y) * xrow(e3.x)[lane];
    }
    for (; j < end; ++j) {
        int2 e = edges[j];
        a0 += __int_as_float(e.y) * xrow(e.x)[lane];
    }
    y[((size_t)wave << 6) + lane] = (a0 + a1) + (a2 + a3);
}

// ---------------- selected-node accumulation ----------------
__global__ __launch_bounds__(256) void k_accsel_init(const float* __restrict__ U,
                                                     const float* __restrict__ I,
                                                     const int* __restrict__ users,
                                                     const int* __restrict__ items,
                                                     float* __restrict__ acc) {
    int gid = blockIdx.x * blockDim.x + threadIdx.x;
    int w = gid >> 6, lane = threadIdx.x & 63;
    if (w >= 2 * BATCH) return;
    const float* src = (w < BATCH) ? U + ((size_t)users[w] << 6)
                                   : I + ((size_t)items[w - BATCH] << 6);
    acc[w * LAT + lane] = src[lane];
}

__global__ __launch_bounds__(256) void k_accsel_add(const float* __restrict__ emb,
                                                    const int* __restrict__ users,
                                                    const int* __restrict__ items,
                                                    float* acc) {
    int gid = blockIdx.x * blockDim.x + threadIdx.x;
    int w = gid >> 6, lane = threadIdx.x & 63;
    if (w >= 2 * BATCH) return;
    int node = (w < BATCH) ? users[w] : (N_USERS + items[w - BATCH]);
    acc[w * LAT + lane] += emb[(size_t)node * LAT + lane];
}

__global__ __launch_bounds__(256) void k_dot(const float* __restrict__ acc,
                                             float* __restrict__ out) {
    int gid = blockIdx.x * blockDim.x + threadIdx.x;
    int w = gid >> 6, lane = threadIdx.x & 63;
    if (w >= BATCH) return;
    float p = acc[w * LAT + lane] * acc[(BATCH + w) * LAT + lane];
    for (int off = 32; off > 0; off >>= 1) p += __shfl_down(p, off, 64);
    if (lane == 0) out[w] = p * (1.0f / 16.0f);   // (/4)·(/4) folded in
}

// ---------------- launch ----------------
extern "C" void kernel_launch(void* const* d_in, const int* in_sizes, int n_in,
                              void* d_out, int out_size, void* d_ws, size_t ws_size,
                              hipStream_t stream) {
    const int*   row_idx  = (const int*)d_in[0];
    const int*   col_idx  = (const int*)d_in[1];
    const float* vals     = (const float*)d_in[2];
    const float* user_emb = (const float*)d_in[3];
    const float* item_emb = (const float*)d_in[4];
    const int*   users    = (const int*)d_in[5];
    const int*   items    = (const int*)d_in[6];
    float*       out      = (float*)d_out;

    char* ws = (char*)d_ws;
    size_t off = 0;
    auto alloc = [&](size_t bytes) -> void* {
        void* p = ws + off;
        off = (off + bytes + 255) & ~(size_t)255;
        return p;
    };
    int*   row_ptr = (int*)alloc((N_NODES + 1) * sizeof(int));
    int*   bcnt    = (int*)alloc(NBUCK * sizeof(int));
    int*   bbase   = (int*)alloc((NBUCK + 1) * sizeof(int));
    int*   bcur    = (int*)alloc(NBUCK * sizeof(int));
    int2*  edges   = (int2*)alloc((size_t)NNZ_C * sizeof(int2));
    float* embA    = (float*)alloc((size_t)N_NODES * LAT * sizeof(float));
    float* embB    = (float*)alloc((size_t)N_NODES * LAT * sizeof(float));
    float* acc     = (float*)alloc((size_t)2 * BATCH * LAT * sizeof(float));

    // tmp (48 MB) aliases embA/embB (76.8 MB): consumed by k_scatter2 before
    // any spmm writes embA.
    int2* tmp = (int2*)embA;

    k_zero<<<(NBUCK + 255) / 256, 256, 0, stream>>>(bcnt, NBUCK);
    k_bucket_hist<<<1024, 256, 0, stream>>>(row_idx, bcnt);
    k_bucket_scan<<<1, 256, 0, stream>>>(bcnt, bbase, bcur, row_ptr);
    k_scatter1<<<2048, 256, 0, stream>>>(row_idx, col_idx, vals, bcur, tmp, NNZ_C);
    k_scatter2<<<NBUCK, 256, 0, stream>>>(bbase, tmp, edges, row_ptr);

    k_accsel_init<<<(2 * BATCH * 64) / 256, 256, 0, stream>>>(user_emb, item_emb,
                                                              users, items, acc);

    k_spmm<true><<<(N_NODES + 3) / 4, 256, 0, stream>>>(row_ptr, edges,
                                                        user_emb, item_emb, embA);
    k_accsel_add<<<(2 * BATCH * 64) / 256, 256, 0, stream>>>(embA, users, items, acc);

    k_spmm<false><<<(N_NODES + 3) / 4, 256, 0, stream>>>(row_ptr, edges,
                                                         embA, nullptr, embB);
    k_accsel_add<<<(2 * BATCH * 64) / 256, 256, 0, stream>>>(embB, users, items, acc);

    k_spmm<false><<<(N_NODES + 3) / 4, 256, 0, stream>>>(row_ptr, edges,
                                                         embB, nullptr, embA);
    k_accsel_add<<<(2 * BATCH * 64) / 256, 256, 0, stream>>>(embA, users, items, acc);

    k_dot<<<(BATCH * 64) / 256, 256, 0, stream>>>(acc, out);
}

// Round 4
// 1143.666 us; speedup vs baseline: 1.6433x; 1.6433x over previous
//
#include <hip/hip_runtime.h>

#define N_USERS 100000
#define N_ITEMS 50000
#define N_NODES 150000
#define NNZ_C   6000000
#define LAT     64
#define BATCH   2048

// ---------------- utility ----------------
__global__ __launch_bounds__(256) void k_zero(int* p, int n) {
    int i = blockIdx.x * blockDim.x + threadIdx.x;
    int stride = gridDim.x * blockDim.x;
    for (; i < n; i += stride) p[i] = 0;
}

// ---------------- hist + per-edge rank (ONE atomic pass total) ----------------
__global__ __launch_bounds__(256) void k_hist_rank(const int* __restrict__ row,
                                                   int* __restrict__ cnt,
                                                   unsigned short* __restrict__ rank) {
    int i = blockIdx.x * blockDim.x + threadIdx.x;
    int stride = gridDim.x * blockDim.x;
    for (; i < NNZ_C; i += stride)
        rank[i] = (unsigned short)atomicAdd(&cnt[row[i]], 1);
}

// block b sums cnt[b*1024 .. b*1024+1023] -> partials[b]
__global__ __launch_bounds__(256) void k_blocksum(const int* __restrict__ cnt,
                                                  int* __restrict__ partials) {
    __shared__ int s[256];
    int base = blockIdx.x * 1024;
    int t = threadIdx.x;
    int sum = 0;
    for (int k = 0; k < 4; ++k) {
        int idx = base + t + k * 256;
        if (idx < N_NODES) sum += cnt[idx];
    }
    s[t] = sum; __syncthreads();
    for (int off = 128; off > 0; off >>= 1) {
        if (t < off) s[t] += s[t + off];
        __syncthreads();
    }
    if (t == 0) partials[blockIdx.x] = s[0];
}

// single block: exclusive scan of partials (nb <= 256); total -> row_ptr[N_NODES]
__global__ __launch_bounds__(256) void k_scan_partials(const int* __restrict__ partials,
                                                       int* __restrict__ scanned,
                                                       int* __restrict__ row_ptr, int nb) {
    __shared__ int s[256];
    int t = threadIdx.x;
    int v = (t < nb) ? partials[t] : 0;
    s[t] = v; __syncthreads();
    for (int off = 1; off < 256; off <<= 1) {
        int x = 0;
        if (t >= off) x = s[t - off];
        __syncthreads();
        s[t] += x;
        __syncthreads();
    }
    scanned[t] = s[t] - v;          // exclusive
    if (t == 255) row_ptr[N_NODES] = s[255];
}

// block b: exclusive scan within its 1024-chunk -> row_ptr
__global__ __launch_bounds__(256) void k_scan_chunk(const int* __restrict__ cnt,
                                                    const int* __restrict__ scanned,
                                                    int* __restrict__ row_ptr) {
    __shared__ int s[256];
    int b = blockIdx.x, t = threadIdx.x;
    int base = b * 1024 + t * 4;
    int v[4];
    int sum = 0;
    for (int k = 0; k < 4; ++k) {
        int idx = base + k;
        v[k] = (idx < N_NODES) ? cnt[idx] : 0;
        sum += v[k];
    }
    int own = sum;
    s[t] = sum; __syncthreads();
    for (int off = 1; off < 256; off <<= 1) {
        int x = 0;
        if (t >= off) x = s[t - off];
        __syncthreads();
        s[t] += x;
        __syncthreads();
    }
    int excl = scanned[b] + s[t] - own;
    for (int k = 0; k < 4; ++k) {
        int idx = base + k;
        if (idx < N_NODES) row_ptr[idx] = excl;
        excl += v[k];
    }
}

// ---------------- atomic-free scatter: pos = row_ptr[row] + rank ----------------
__global__ __launch_bounds__(256) void k_scatter(const int* __restrict__ row,
                                                 const int* __restrict__ col,
                                                 const float* __restrict__ vals,
                                                 const unsigned short* __restrict__ rank,
                                                 const int* __restrict__ row_ptr,
                                                 int2* __restrict__ edges) {
    int i = blockIdx.x * blockDim.x + threadIdx.x;
    int stride = gridDim.x * blockDim.x;
    for (; i < NNZ_C; i += stride) {
        int r = row[i];
        int pos = row_ptr[r] + (int)rank[i];
        edges[pos] = make_int2(col[i], __float_as_int(vals[i]));
    }
}

// ---------------- SpMM: wave per row, lane = latent dim ----------------
template <bool SPLIT>
__global__ __launch_bounds__(256) void k_spmm(const int* __restrict__ row_ptr,
                                              const int2* __restrict__ edges,
                                              const float* __restrict__ x0,
                                              const float* __restrict__ x1,
                                              float* __restrict__ y) {
    int wv = (int)((blockIdx.x * blockDim.x + threadIdx.x) >> 6);
    int wave = __builtin_amdgcn_readfirstlane(wv);
    int lane = threadIdx.x & 63;
    if (wave >= N_NODES) return;
    int beg = row_ptr[wave], end = row_ptr[wave + 1];
    float a0 = 0.f, a1 = 0.f, a2 = 0.f, a3 = 0.f;
    auto xrow = [&](int c) -> const float* {
        if (SPLIT)
            return (c < N_USERS) ? x0 + ((size_t)c << 6)
                                 : x1 + ((size_t)(c - N_USERS) << 6);
        return x0 + ((size_t)c << 6);
    };
    int j = beg;
    for (; j + 4 <= end; j += 4) {
        int2 e0 = edges[j], e1 = edges[j + 1], e2 = edges[j + 2], e3 = edges[j + 3];
        a0 += __int_as_float(e0.y) * xrow(e0.x)[lane];
        a1 += __int_as_float(e1.y) * xrow(e1.x)[lane];
        a2 += __int_as_float(e2.y) * xrow(e2.x)[lane];
        a3 += __int_as_float(e3.y) * xrow(e3.x)[lane];
    }
    for (; j < end; ++j) {
        int2 e = edges[j];
        a0 += __int_as_float(e.y) * xrow(e.x)[lane];
    }
    y[((size_t)wave << 6) + lane] = (a0 + a1) + (a2 + a3);
}

// ---------------- selected-node accumulation ----------------
__global__ __launch_bounds__(256) void k_accsel_init(const float* __restrict__ U,
                                                     const float* __restrict__ I,
                                                     const int* __restrict__ users,
                                                     const int* __restrict__ items,
                                                     float* __restrict__ acc) {
    int gid = blockIdx.x * blockDim.x + threadIdx.x;
    int w = gid >> 6, lane = threadIdx.x & 63;
    if (w >= 2 * BATCH) return;
    const float* src = (w < BATCH) ? U + ((size_t)users[w] << 6)
                                   : I + ((size_t)items[w - BATCH] << 6);
    acc[w * LAT + lane] = src[lane];
}

__global__ __launch_bounds__(256) void k_accsel_add(const float* __restrict__ emb,
                                                    const int* __restrict__ users,
                                                    const int* __restrict__ items,
                                                    float* acc) {
    int gid = blockIdx.x * blockDim.x + threadIdx.x;
    int w = gid >> 6, lane = threadIdx.x & 63;
    if (w >= 2 * BATCH) return;
    int node = (w < BATCH) ? users[w] : (N_USERS + items[w - BATCH]);
    acc[w * LAT + lane] += emb[(size_t)node * LAT + lane];
}

__global__ __launch_bounds__(256) void k_dot(const float* __restrict__ acc,
                                             float* __restrict__ out) {
    int gid = blockIdx.x * blockDim.x + threadIdx.x;
    int w = gid >> 6, lane = threadIdx.x & 63;
    if (w >= BATCH) return;
    float p = acc[w * LAT + lane] * acc[(BATCH + w) * LAT + lane];
    for (int off = 32; off > 0; off >>= 1) p += __shfl_down(p, off, 64);
    if (lane == 0) out[w] = p * (1.0f / 16.0f);   // (/4)·(/4) folded in
}

// ---------------- launch ----------------
extern "C" void kernel_launch(void* const* d_in, const int* in_sizes, int n_in,
                              void* d_out, int out_size, void* d_ws, size_t ws_size,
                              hipStream_t stream) {
    const int*   row_idx  = (const int*)d_in[0];
    const int*   col_idx  = (const int*)d_in[1];
    const float* vals     = (const float*)d_in[2];
    const float* user_emb = (const float*)d_in[3];
    const float* item_emb = (const float*)d_in[4];
    const int*   users    = (const int*)d_in[5];
    const int*   items    = (const int*)d_in[6];
    float*       out      = (float*)d_out;

    char* ws = (char*)d_ws;
    size_t off = 0;
    auto alloc = [&](size_t bytes) -> void* {
        void* p = ws + off;
        off = (off + bytes + 255) & ~(size_t)255;
        return p;
    };
    int*            row_ptr  = (int*)alloc((N_NODES + 1) * sizeof(int));
    int*            cnt      = (int*)alloc((size_t)N_NODES * sizeof(int));
    int*            partials = (int*)alloc(256 * sizeof(int));
    int*            scanned  = (int*)alloc(256 * sizeof(int));
    unsigned short* rank     = (unsigned short*)alloc((size_t)NNZ_C * sizeof(unsigned short));
    int2*           edges    = (int2*)alloc((size_t)NNZ_C * sizeof(int2));
    float*          embA     = (float*)alloc((size_t)N_NODES * LAT * sizeof(float));
    float*          embB     = (float*)alloc((size_t)N_NODES * LAT * sizeof(float));
    float*          acc      = (float*)alloc((size_t)2 * BATCH * LAT * sizeof(float));

    const int nb_chunks = (N_NODES + 1023) / 1024;   // 147

    k_zero<<<256, 256, 0, stream>>>(cnt, N_NODES);
    k_hist_rank<<<2048, 256, 0, stream>>>(row_idx, cnt, rank);
    k_blocksum<<<nb_chunks, 256, 0, stream>>>(cnt, partials);
    k_scan_partials<<<1, 256, 0, stream>>>(partials, scanned, row_ptr, nb_chunks);
    k_scan_chunk<<<nb_chunks, 256, 0, stream>>>(cnt, scanned, row_ptr);
    k_scatter<<<2048, 256, 0, stream>>>(row_idx, col_idx, vals, rank, row_ptr, edges);

    k_accsel_init<<<(2 * BATCH * 64) / 256, 256, 0, stream>>>(user_emb, item_emb,
                                                              users, items, acc);

    k_spmm<true><<<(N_NODES + 3) / 4, 256, 0, stream>>>(row_ptr, edges,
                                                        user_emb, item_emb, embA);
    k_accsel_add<<<(2 * BATCH * 64) / 256, 256, 0, stream>>>(embA, users, items, acc);

    k_spmm<false><<<(N_NODES + 3) / 4, 256, 0, stream>>>(row_ptr, edges,
                                                         embA, nullptr, embB);
    k_accsel_add<<<(2 * BATCH * 64) / 256, 256, 0, stream>>>(embB, users, items, acc);

    k_spmm<false><<<(N_NODES + 3) / 4, 256, 0, stream>>>(row_ptr, edges,
                                                         embB, nullptr, embA);
    k_accsel_add<<<(2 * BATCH * 64) / 256, 256, 0, stream>>>(embA, users, items, acc);

    k_dot<<<(BATCH * 64) / 256, 256, 0, stream>>>(acc, out);
}

// Round 6
// 964.999 us; speedup vs baseline: 1.9476x; 1.1851x over previous
//
#include <hip/hip_runtime.h>

#define N_USERS 100000
#define N_ITEMS 50000
#define N_NODES 150000
#define NNZ_C   6000000
#define LAT     64
#define BATCH   2048

// ---------------- utility ----------------
__global__ __launch_bounds__(256) void k_zero(int* p, int n) {
    int i = blockIdx.x * blockDim.x + threadIdx.x;
    int stride = gridDim.x * blockDim.x;
    for (; i < n; i += stride) p[i] = 0;
}

// ---------------- hist + per-edge rank (ONE atomic pass total) ----------------
__global__ __launch_bounds__(256) void k_hist_rank(const int* __restrict__ row,
                                                   int* __restrict__ cnt,
                                                   unsigned short* __restrict__ rank) {
    int i = blockIdx.x * blockDim.x + threadIdx.x;
    int stride = gridDim.x * blockDim.x;
    for (; i < NNZ_C; i += stride)
        rank[i] = (unsigned short)atomicAdd(&cnt[row[i]], 1);
}

// block b sums cnt[b*1024 .. b*1024+1023] -> partials[b]
__global__ __launch_bounds__(256) void k_blocksum(const int* __restrict__ cnt,
                                                  int* __restrict__ partials) {
    __shared__ int s[256];
    int base = blockIdx.x * 1024;
    int t = threadIdx.x;
    int sum = 0;
    for (int k = 0; k < 4; ++k) {
        int idx = base + t + k * 256;
        if (idx < N_NODES) sum += cnt[idx];
    }
    s[t] = sum; __syncthreads();
    for (int off = 128; off > 0; off >>= 1) {
        if (t < off) s[t] += s[t + off];
        __syncthreads();
    }
    if (t == 0) partials[blockIdx.x] = s[0];
}

// single block: exclusive scan of partials (nb <= 256); total -> row_ptr[N_NODES]
__global__ __launch_bounds__(256) void k_scan_partials(const int* __restrict__ partials,
                                                       int* __restrict__ scanned,
                                                       int* __restrict__ row_ptr, int nb) {
    __shared__ int s[256];
    int t = threadIdx.x;
    int v = (t < nb) ? partials[t] : 0;
    s[t] = v; __syncthreads();
    for (int off = 1; off < 256; off <<= 1) {
        int x = 0;
        if (t >= off) x = s[t - off];
        __syncthreads();
        s[t] += x;
        __syncthreads();
    }
    scanned[t] = s[t] - v;          // exclusive
    if (t == 255) row_ptr[N_NODES] = s[255];
}

// block b: exclusive scan within its 1024-chunk -> row_ptr
__global__ __launch_bounds__(256) void k_scan_chunk(const int* __restrict__ cnt,
                                                    const int* __restrict__ scanned,
                                                    int* __restrict__ row_ptr) {
    __shared__ int s[256];
    int b = blockIdx.x, t = threadIdx.x;
    int base = b * 1024 + t * 4;
    int v[4];
    int sum = 0;
    for (int k = 0; k < 4; ++k) {
        int idx = base + k;
        v[k] = (idx < N_NODES) ? cnt[idx] : 0;
        sum += v[k];
    }
    int own = sum;
    s[t] = sum; __syncthreads();
    for (int off = 1; off < 256; off <<= 1) {
        int x = 0;
        if (t >= off) x = s[t - off];
        __syncthreads();
        s[t] += x;
        __syncthreads();
    }
    int excl = scanned[b] + s[t] - own;
    for (int k = 0; k < 4; ++k) {
        int idx = base + k;
        if (idx < N_NODES) row_ptr[idx] = excl;
        excl += v[k];
    }
}

// ---------------- atomic-free scatter: pos = row_ptr[row] + rank ----------------
__global__ __launch_bounds__(256) void k_scatter(const int* __restrict__ row,
                                                 const int* __restrict__ col,
                                                 const float* __restrict__ vals,
                                                 const unsigned short* __restrict__ rank,
                                                 const int* __restrict__ row_ptr,
                                                 int2* __restrict__ edges) {
    int i = blockIdx.x * blockDim.x + threadIdx.x;
    int stride = gridDim.x * blockDim.x;
    for (; i < NNZ_C; i += stride) {
        int r = row[i];
        int pos = row_ptr[r] + (int)rank[i];
        edges[pos] = make_int2(col[i], __float_as_int(vals[i]));
    }
}

// ---------------- SpMM: wave per row, lane = latent dim ----------------
template <bool SPLIT>
__global__ __launch_bounds__(256) void k_spmm(const int* __restrict__ row_ptr,
                                              const int2* __restrict__ edges,
                                              const float* __restrict__ x0,
                                              const float* __restrict__ x1,
                                              float* __restrict__ y) {
    int wv = (int)((blockIdx.x * blockDim.x + threadIdx.x) >> 6);
    int wave = __builtin_amdgcn_readfirstlane(wv);
    int lane = threadIdx.x & 63;
    if (wave >= N_NODES) return;
    int beg = row_ptr[wave], end = row_ptr[wave + 1];
    float a0 = 0.f, a1 = 0.f, a2 = 0.f, a3 = 0.f;
    auto xrow = [&](int c) -> const float* {
        if (SPLIT)
            return (c < N_USERS) ? x0 + ((size_t)c << 6)
                                 : x1 + ((size_t)(c - N_USERS) << 6);
        return x0 + ((size_t)c << 6);
    };
    int j = beg;
    for (; j + 4 <= end; j += 4) {
        int2 e0 = edges[j], e1 = edges[j + 1], e2 = edges[j + 2], e3 = edges[j + 3];
        a0 += __int_as_float(e0.y) * xrow(e0.x)[lane];
        a1 += __int_as_float(e1.y) * xrow(e1.x)[lane];
        a2 += __int_as_float(e2.y) * xrow(e2.x)[lane];
        a3 += __int_as_float(e3.y) * xrow(e3.x)[lane];
    }
    for (; j < end; ++j) {
        int2 e = edges[j];
        a0 += __int_as_float(e.y) * xrow(e.x)[lane];
    }
    y[((size_t)wave << 6) + lane] = (a0 + a1) + (a2 + a3);
}

// ---------------- partial SpMM over the 4096 selected rows: acc += (A·x)[sel] ----------------
__global__ __launch_bounds__(256) void k_spmm_sel(const int* __restrict__ row_ptr,
                                                  const int2* __restrict__ edges,
                                                  const float* __restrict__ x,
                                                  const int* __restrict__ users,
                                                  const int* __restrict__ items,
                                                  float* __restrict__ acc) {
    int w = (int)((blockIdx.x * blockDim.x + threadIdx.x) >> 6);
    int lane = threadIdx.x & 63;
    if (w >= 2 * BATCH) return;
    int node = (w < BATCH) ? users[w] : (N_USERS + items[w - BATCH]);
    node = __builtin_amdgcn_readfirstlane(node);
    int beg = row_ptr[node], end = row_ptr[node + 1];
    float a0 = 0.f, a1 = 0.f;
    int j = beg;
    for (; j + 2 <= end; j += 2) {
        int2 e0 = edges[j], e1 = edges[j + 1];
        a0 += __int_as_float(e0.y) * x[((size_t)e0.x << 6) + lane];
        a1 += __int_as_float(e1.y) * x[((size_t)e1.x << 6) + lane];
    }
    if (j < end) {
        int2 e = edges[j];
        a0 += __int_as_float(e.y) * x[((size_t)e.x << 6) + lane];
    }
    acc[w * LAT + lane] += a0 + a1;
}

// ---------------- selected-node accumulation ----------------
__global__ __launch_bounds__(256) void k_accsel_init(const float* __restrict__ U,
                                                     const float* __restrict__ I,
                                                     const int* __restrict__ users,
                                                     const int* __restrict__ items,
                                                     float* __restrict__ acc) {
    int gid = blockIdx.x * blockDim.x + threadIdx.x;
    int w = gid >> 6, lane = threadIdx.x & 63;
    if (w >= 2 * BATCH) return;
    const float* src = (w < BATCH) ? U + ((size_t)users[w] << 6)
                                   : I + ((size_t)items[w - BATCH] << 6);
    acc[w * LAT + lane] = src[lane];
}

__global__ __launch_bounds__(256) void k_accsel_add(const float* __restrict__ emb,
                                                    const int* __restrict__ users,
                                                    const int* __restrict__ items,
                                                    float* acc) {
    int gid = blockIdx.x * blockDim.x + threadIdx.x;
    int w = gid >> 6, lane = threadIdx.x & 63;
    if (w >= 2 * BATCH) return;
    int node = (w < BATCH) ? users[w] : (N_USERS + items[w - BATCH]);
    acc[w * LAT + lane] += emb[(size_t)node * LAT + lane];
}

__global__ __launch_bounds__(256) void k_dot(const float* __restrict__ acc,
                                             float* __restrict__ out) {
    int gid = blockIdx.x * blockDim.x + threadIdx.x;
    int w = gid >> 6, lane = threadIdx.x & 63;
    if (w >= BATCH) return;
    float p = acc[w * LAT + lane] * acc[(BATCH + w) * LAT + lane];
    for (int off = 32; off > 0; off >>= 1) p += __shfl_down(p, off, 64);
    if (lane == 0) out[w] = p * (1.0f / 16.0f);   // (/4)·(/4) folded in
}

// ---------------- launch ----------------
extern "C" void kernel_launch(void* const* d_in, const int* in_sizes, int n_in,
                              void* d_out, int out_size, void* d_ws, size_t ws_size,
                              hipStream_t stream) {
    const int*   row_idx  = (const int*)d_in[0];
    const int*   col_idx  = (const int*)d_in[1];
    const float* vals     = (const float*)d_in[2];
    const float* user_emb = (const float*)d_in[3];
    const float* item_emb = (const float*)d_in[4];
    const int*   users    = (const int*)d_in[5];
    const int*   items    = (const int*)d_in[6];
    float*       out      = (float*)d_out;

    char* ws = (char*)d_ws;
    size_t off = 0;
    auto alloc = [&](size_t bytes) -> void* {
        void* p = ws + off;
        off = (off + bytes + 255) & ~(size_t)255;
        return p;
    };
    int*            row_ptr  = (int*)alloc((N_NODES + 1) * sizeof(int));
    int*            cnt      = (int*)alloc((size_t)N_NODES * sizeof(int));
    int*            partials = (int*)alloc(256 * sizeof(int));
    int*            scanned  = (int*)alloc(256 * sizeof(int));
    unsigned short* rank     = (unsigned short*)alloc((size_t)NNZ_C * sizeof(unsigned short));
    int2*           edges    = (int2*)alloc((size_t)NNZ_C * sizeof(int2));
    float*          embA     = (float*)alloc((size_t)N_NODES * LAT * sizeof(float));
    float*          embB     = (float*)alloc((size_t)N_NODES * LAT * sizeof(float));
    float*          acc      = (float*)alloc((size_t)2 * BATCH * LAT * sizeof(float));

    const int nb_chunks = (N_NODES + 1023) / 1024;   // 147

    // ---- CSR build ----
    k_zero<<<256, 256, 0, stream>>>(cnt, N_NODES);
    k_hist_rank<<<2048, 256, 0, stream>>>(row_idx, cnt, rank);
    k_blocksum<<<nb_chunks, 256, 0, stream>>>(cnt, partials);
    k_scan_partials<<<1, 256, 0, stream>>>(partials, scanned, row_ptr, nb_chunks);
    k_scan_chunk<<<nb_chunks, 256, 0, stream>>>(cnt, scanned, row_ptr);
    k_scatter<<<2048, 256, 0, stream>>>(row_idx, col_idx, vals, rank, row_ptr, edges);

    // ---- acc = e0[sel] ----
    k_accsel_init<<<(2 * BATCH * 64) / 256, 256, 0, stream>>>(user_emb, item_emb,
                                                              users, items, acc);

    // ---- B = A·e0 (full), acc += B[sel] ----
    k_spmm<true><<<(N_NODES + 3) / 4, 256, 0, stream>>>(row_ptr, edges,
                                                        user_emb, item_emb, embA);
    k_accsel_add<<<(2 * BATCH * 64) / 256, 256, 0, stream>>>(embA, users, items, acc);

    // ---- C = A·B (full), acc += C[sel] ----
    k_spmm<false><<<(N_NODES + 3) / 4, 256, 0, stream>>>(row_ptr, edges,
                                                         embA, nullptr, embB);
    k_accsel_add<<<(2 * BATCH * 64) / 256, 256, 0, stream>>>(embB, users, items, acc);

    // ---- acc += (A·C)[sel] — partial SpMM over 4096 selected rows only ----
    k_spmm_sel<<<(2 * BATCH * 64) / 256, 256, 0, stream>>>(row_ptr, edges, embB,
                                                           users, items, acc);

    // ---- gamma ----
    k_dot<<<(BATCH * 64) / 256, 256, 0, stream>>>(acc, out);
}

// Round 9
// 881.060 us; speedup vs baseline: 2.1331x; 1.0953x over previous
//
#include <hip/hip_runtime.h>

#define N_USERS 100000
#define N_ITEMS 50000
#define N_NODES 150000
#define NNZ_C   6000000
#define LAT     64
#define BATCH   2048

#define BROWS2   256                                  // rows per bucket (shiftable)
#define NBUCK2   ((N_NODES + BROWS2 - 1) / BROWS2)    // 586
#define NBLK_A   512
#define CHUNK_A  ((NNZ_C + NBLK_A - 1) / NBLK_A)      // 11719

// ---------------- utility ----------------
__global__ __launch_bounds__(256) void k_zero(int* p, int n) {
    int i = blockIdx.x * blockDim.x + threadIdx.x;
    if (i < n) p[i] = 0;
}

// ---------------- phase A1: bucket counts via LDS hist (no per-edge global atomics) ----------------
__global__ __launch_bounds__(256) void k_bucket_count(const int* __restrict__ row,
                                                      int* __restrict__ bcnt) {
    __shared__ int h[NBUCK2];
    for (int k = threadIdx.x; k < NBUCK2; k += 256) h[k] = 0;
    __syncthreads();
    int beg = blockIdx.x * CHUNK_A;
    int end = min(beg + CHUNK_A, NNZ_C);
    for (int i = beg + threadIdx.x; i < end; i += 256)
        atomicAdd(&h[row[i] >> 8], 1);
    __syncthreads();
    for (int k = threadIdx.x; k < NBUCK2; k += 256) {
        int v = h[k];
        if (v) atomicAdd(&bcnt[k], v);
    }
}

// ---------------- bucket scan: bbase/bcur; row_ptr[N] = NNZ ----------------
__global__ __launch_bounds__(256) void k_bucket_scan(const int* __restrict__ bcnt,
                                                     int* __restrict__ bbase,
                                                     int* __restrict__ bcur,
                                                     int* __restrict__ row_ptr) {
    __shared__ int s[256];
    __shared__ int carry;
    int t = threadIdx.x;
    if (t == 0) carry = 0;
    __syncthreads();
    for (int c0 = 0; c0 < NBUCK2; c0 += 256) {
        int idx = c0 + t;
        int v = (idx < NBUCK2) ? bcnt[idx] : 0;
        s[t] = v; __syncthreads();
        for (int off = 1; off < 256; off <<= 1) {
            int x = (t >= off) ? s[t - off] : 0;
            __syncthreads();
            s[t] += x;
            __syncthreads();
        }
        int excl = carry + s[t] - v;
        if (idx < NBUCK2) { bbase[idx] = excl; bcur[idx] = excl; }
        __syncthreads();
        if (t == 255) carry += s[255];
        __syncthreads();
    }
    if (t == 0) { bbase[NBUCK2] = carry; row_ptr[N_NODES] = carry; }
}

// ---------------- phase A2: scatter into bucket-grouped SoA (block-private sub-ranges) ----------------
__global__ __launch_bounds__(256) void k_bucket_scatter(const int* __restrict__ row,
                                                        const int* __restrict__ col,
                                                        const float* __restrict__ vals,
                                                        int* __restrict__ bcur,
                                                        int* __restrict__ keys,
                                                        float* __restrict__ valsT) {
    __shared__ int h[NBUCK2];
    __shared__ int base[NBUCK2];
    for (int k = threadIdx.x; k < NBUCK2; k += 256) h[k] = 0;
    __syncthreads();
    int beg = blockIdx.x * CHUNK_A;
    int end = min(beg + CHUNK_A, NNZ_C);
    for (int i = beg + threadIdx.x; i < end; i += 256)
        atomicAdd(&h[row[i] >> 8], 1);
    __syncthreads();
    for (int k = threadIdx.x; k < NBUCK2; k += 256) {
        int v = h[k];
        base[k] = v ? atomicAdd(&bcur[k], v) : 0;   // reserve private sub-range
    }
    __syncthreads();
    for (int k = threadIdx.x; k < NBUCK2; k += 256) h[k] = 0;  // reuse as local cursor
    __syncthreads();
    for (int i = beg + threadIdx.x; i < end; i += 256) {
        int r = row[i];
        int b = r >> 8;
        int ofs = atomicAdd(&h[b], 1);
        int pos = base[b] + ofs;
        keys[pos]  = ((r & 255) << 18) | col[i];    // lrow:8b | col:18b
        valsT[pos] = vals[i];
    }
}

// ---------------- phase B: per-bucket counting sort -> final CSR + row_ptr ----------------
__global__ __launch_bounds__(256) void k_csr_build(const int* __restrict__ bbase,
                                                   const int* __restrict__ keys,
                                                   const float* __restrict__ valsT,
                                                   int2* __restrict__ edges,
                                                   int* __restrict__ row_ptr) {
    __shared__ int cnt[BROWS2];
    __shared__ int scn[BROWS2];
    __shared__ int cur[BROWS2];
    int b = blockIdx.x, t = threadIdx.x;
    int beg = bbase[b], end = bbase[b + 1];
    cnt[t] = 0;
    __syncthreads();
    for (int i = beg + t; i < end; i += 256)
        atomicAdd(&cnt[keys[i] >> 18], 1);
    __syncthreads();
    int v = cnt[t];
    scn[t] = v;
    __syncthreads();
    for (int off = 1; off < 256; off <<= 1) {
        int x = (t >= off) ? scn[t - off] : 0;
        __syncthreads();
        scn[t] += x;
        __syncthreads();
    }
    int excl = beg + scn[t] - v;
    cur[t] = excl;
    int g = b * BROWS2 + t;
    if (g < N_NODES) row_ptr[g] = excl;
    __syncthreads();
    for (int i = beg + t; i < end; i += 256) {
        int k = keys[i];
        int pos = atomicAdd(&cur[k >> 18], 1);
        edges[pos] = make_int2(k & 0x3FFFF, __float_as_int(valsT[i]));
    }
}

// ---------------- SpMM: wave per row, lane = latent dim ----------------
template <bool SPLIT>
__global__ __launch_bounds__(256) void k_spmm(const int* __restrict__ row_ptr,
                                              const int2* __restrict__ edges,
                                              const float* __restrict__ x0,
                                              const float* __restrict__ x1,
                                              float* __restrict__ y) {
    int wv = (int)((blockIdx.x * blockDim.x + threadIdx.x) >> 6);
    int wave = __builtin_amdgcn_readfirstlane(wv);
    int lane = threadIdx.x & 63;
    if (wave >= N_NODES) return;
    int beg = row_ptr[wave], end = row_ptr[wave + 1];
    float a0 = 0.f, a1 = 0.f, a2 = 0.f, a3 = 0.f;
    auto xrow = [&](int c) -> const float* {
        if (SPLIT)
            return (c < N_USERS) ? x0 + ((size_t)c << 6)
                                 : x1 + ((size_t)(c - N_USERS) << 6);
        return x0 + ((size_t)c << 6);
    };
    int j = beg;
    for (; j + 4 <= end; j += 4) {
        int2 e0 = edges[j], e1 = edges[j + 1], e2 = edges[j + 2], e3 = edges[j + 3];
        a0 += __int_as_float(e0.y) * xrow(e0.x)[lane];
        a1 += __int_as_float(e1.y) * xrow(e1.x)[lane];
        a2 += __int_as_float(e2.y) * xrow(e2.x)[lane];
        a3 += __int_as_float(e3.y) * xrow(e3.x)[lane];
    }
    for (; j < end; ++j) {
        int2 e = edges[j];
        a0 += __int_as_float(e.y) * xrow(e.x)[lane];
    }
    y[((size_t)wave << 6) + lane] = (a0 + a1) + (a2 + a3);
}

// ---------------- partial SpMM over the 4096 selected rows: acc += (A·x)[sel] ----------------
__global__ __launch_bounds__(256) void k_spmm_sel(const int* __restrict__ row_ptr,
                                                  const int2* __restrict__ edges,
                                                  const float* __restrict__ x,
                                                  const int* __restrict__ users,
                                                  const int* __restrict__ items,
                                                  float* __restrict__ acc) {
    int w = (int)((blockIdx.x * blockDim.x + threadIdx.x) >> 6);
    int lane = threadIdx.x & 63;
    if (w >= 2 * BATCH) return;
    int node = (w < BATCH) ? users[w] : (N_USERS + items[w - BATCH]);
    node = __builtin_amdgcn_readfirstlane(node);
    int beg = row_ptr[node], end = row_ptr[node + 1];
    float a0 = 0.f, a1 = 0.f;
    int j = beg;
    for (; j + 2 <= end; j += 2) {
        int2 e0 = edges[j], e1 = edges[j + 1];
        a0 += __int_as_float(e0.y) * x[((size_t)e0.x << 6) + lane];
        a1 += __int_as_float(e1.y) * x[((size_t)e1.x << 6) + lane];
    }
    if (j < end) {
        int2 e = edges[j];
        a0 += __int_as_float(e.y) * x[((size_t)e.x << 6) + lane];
    }
    acc[w * LAT + lane] += a0 + a1;
}

// ---------------- selected-node accumulation ----------------
__global__ __launch_bounds__(256) void k_accsel_init(const float* __restrict__ U,
                                                     const float* __restrict__ I,
                                                     const int* __restrict__ users,
                                                     const int* __restrict__ items,
                                                     float* __restrict__ acc) {
    int gid = blockIdx.x * blockDim.x + threadIdx.x;
    int w = gid >> 6, lane = threadIdx.x & 63;
    if (w >= 2 * BATCH) return;
    const float* src = (w < BATCH) ? U + ((size_t)users[w] << 6)
                                   : I + ((size_t)items[w - BATCH] << 6);
    acc[w * LAT + lane] = src[lane];
}

__global__ __launch_bounds__(256) void k_accsel_add(const float* __restrict__ emb,
                                                    const int* __restrict__ users,
                                                    const int* __restrict__ items,
                                                    float* acc) {
    int gid = blockIdx.x * blockDim.x + threadIdx.x;
    int w = gid >> 6, lane = threadIdx.x & 63;
    if (w >= 2 * BATCH) return;
    int node = (w < BATCH) ? users[w] : (N_USERS + items[w - BATCH]);
    acc[w * LAT + lane] += emb[(size_t)node * LAT + lane];
}

__global__ __launch_bounds__(256) void k_dot(const float* __restrict__ acc,
                                             float* __restrict__ out) {
    int gid = blockIdx.x * blockDim.x + threadIdx.x;
    int w = gid >> 6, lane = threadIdx.x & 63;
    if (w >= BATCH) return;
    float p = acc[w * LAT + lane] * acc[(BATCH + w) * LAT + lane];
    for (int off = 32; off > 0; off >>= 1) p += __shfl_down(p, off, 64);
    if (lane == 0) out[w] = p * (1.0f / 16.0f);   // (/4)·(/4) folded in
}

// ---------------- launch ----------------
extern "C" void kernel_launch(void* const* d_in, const int* in_sizes, int n_in,
                              void* d_out, int out_size, void* d_ws, size_t ws_size,
                              hipStream_t stream) {
    const int*   row_idx  = (const int*)d_in[0];
    const int*   col_idx  = (const int*)d_in[1];
    const float* vals     = (const float*)d_in[2];
    const float* user_emb = (const float*)d_in[3];
    const float* item_emb = (const float*)d_in[4];
    const int*   users    = (const int*)d_in[5];
    const int*   items    = (const int*)d_in[6];
    float*       out      = (float*)d_out;

    char* ws = (char*)d_ws;
    size_t off = 0;
    auto alloc = [&](size_t bytes) -> void* {
        void* p = ws + off;
        off = (off + bytes + 255) & ~(size_t)255;
        return p;
    };
    int*   row_ptr = (int*)alloc((N_NODES + 1) * sizeof(int));
    int*   bcnt    = (int*)alloc(NBUCK2 * sizeof(int));
    int*   bbase   = (int*)alloc((NBUCK2 + 1) * sizeof(int));
    int*   bcur    = (int*)alloc(NBUCK2 * sizeof(int));
    int2*  edges   = (int2*)alloc((size_t)NNZ_C * sizeof(int2));
    float* embA    = (float*)alloc((size_t)N_NODES * LAT * sizeof(float));
    float* embB    = (float*)alloc((size_t)N_NODES * LAT * sizeof(float));
    float* acc     = (float*)alloc((size_t)2 * BATCH * LAT * sizeof(float));

    // phase-A staging aliases embA/embB (consumed by k_csr_build before any SpMM writes)
    int*   keys  = (int*)embA;     // 24 MB < 38.4 MB
    float* valsT = (float*)embB;   // 24 MB < 38.4 MB

    // ---- CSR build (two-level LDS counting sort, no per-edge global atomics) ----
    k_zero<<<(NBUCK2 + 255) / 256, 256, 0, stream>>>(bcnt, NBUCK2);
    k_bucket_count<<<NBLK_A, 256, 0, stream>>>(row_idx, bcnt);
    k_bucket_scan<<<1, 256, 0, stream>>>(bcnt, bbase, bcur, row_ptr);
    k_bucket_scatter<<<NBLK_A, 256, 0, stream>>>(row_idx, col_idx, vals, bcur, keys, valsT);
    k_csr_build<<<NBUCK2, 256, 0, stream>>>(bbase, keys, valsT, edges, row_ptr);

    // ---- acc = e0[sel] ----
    k_accsel_init<<<(2 * BATCH * 64) / 256, 256, 0, stream>>>(user_emb, item_emb,
                                                              users, items, acc);

    // ---- B = A·e0 (full), acc += B[sel] ----
    k_spmm<true><<<(N_NODES + 3) / 4, 256, 0, stream>>>(row_ptr, edges,
                                                        user_emb, item_emb, embA);
    k_accsel_add<<<(2 * BATCH * 64) / 256, 256, 0, stream>>>(embA, users, items, acc);

    // ---- C = A·B (full), acc += C[sel] ----
    k_spmm<false><<<(N_NODES + 3) / 4, 256, 0, stream>>>(row_ptr, edges,
                                                         embA, nullptr, embB);
    k_accsel_add<<<(2 * BATCH * 64) / 256, 256, 0, stream>>>(embB, users, items, acc);

    // ---- acc += (A·C)[sel] — partial SpMM over 4096 selected rows only ----
    k_spmm_sel<<<(2 * BATCH * 64) / 256, 256, 0, stream>>>(row_ptr, edges, embB,
                                                           users, items, acc);

    // ---- gamma ----
    k_dot<<<(BATCH * 64) / 256, 256, 0, stream>>>(acc, out);
}

// Round 10
// 796.005 us; speedup vs baseline: 2.3611x; 1.1069x over previous
//
#include <hip/hip_runtime.h>

#define N_USERS 100000
#define N_ITEMS 50000
#define N_NODES 150000
#define NNZ_C   6000000
#define LAT     64
#define BATCH   2048

#define BROWS2   256                                  // rows per bucket
#define NBUCK2   ((N_NODES + BROWS2 - 1) / BROWS2)    // 586
#define NBLK_A   256
#define CHUNK_A  ((NNZ_C + NBLK_A - 1) / NBLK_A)      // 23438

// ---------------- utility ----------------
__global__ __launch_bounds__(256) void k_zero(int* p, int n) {
    int i = blockIdx.x * blockDim.x + threadIdx.x;
    if (i < n) p[i] = 0;
}

// ---------------- phase A1: bucket counts via LDS hist (no per-edge global atomics) ----------------
__global__ __launch_bounds__(256) void k_bucket_count(const int* __restrict__ row,
                                                      int* __restrict__ bcnt) {
    __shared__ int h[NBUCK2];
    for (int k = threadIdx.x; k < NBUCK2; k += 256) h[k] = 0;
    __syncthreads();
    int beg = blockIdx.x * CHUNK_A;
    int end = min(beg + CHUNK_A, NNZ_C);
    for (int i = beg + threadIdx.x; i < end; i += 256)
        atomicAdd(&h[row[i] >> 8], 1);
    __syncthreads();
    for (int k = threadIdx.x; k < NBUCK2; k += 256) {
        int v = h[k];
        if (v) atomicAdd(&bcnt[k], v);
    }
}

// ---------------- bucket scan: bbase/bcur; row_ptr[N] = NNZ ----------------
__global__ __launch_bounds__(256) void k_bucket_scan(const int* __restrict__ bcnt,
                                                     int* __restrict__ bbase,
                                                     int* __restrict__ bcur,
                                                     int* __restrict__ row_ptr) {
    __shared__ int s[256];
    __shared__ int carry;
    int t = threadIdx.x;
    if (t == 0) carry = 0;
    __syncthreads();
    for (int c0 = 0; c0 < NBUCK2; c0 += 256) {
        int idx = c0 + t;
        int v = (idx < NBUCK2) ? bcnt[idx] : 0;
        s[t] = v; __syncthreads();
        for (int off = 1; off < 256; off <<= 1) {
            int x = (t >= off) ? s[t - off] : 0;
            __syncthreads();
            s[t] += x;
            __syncthreads();
        }
        int excl = carry + s[t] - v;
        if (idx < NBUCK2) { bbase[idx] = excl; bcur[idx] = excl; }
        __syncthreads();
        if (t == 255) carry += s[255];
        __syncthreads();
    }
    if (t == 0) { bbase[NBUCK2] = carry; row_ptr[N_NODES] = carry; }
}

// ---------------- phase A2: scatter into bucket-grouped AoS (block-private sub-ranges) ----------------
__global__ __launch_bounds__(256) void k_bucket_scatter(const int* __restrict__ row,
                                                        const int* __restrict__ col,
                                                        const float* __restrict__ vals,
                                                        int* __restrict__ bcur,
                                                        int2* __restrict__ tmp) {
    __shared__ int h[NBUCK2];
    __shared__ int base[NBUCK2];
    for (int k = threadIdx.x; k < NBUCK2; k += 256) h[k] = 0;
    __syncthreads();
    int beg = blockIdx.x * CHUNK_A;
    int end = min(beg + CHUNK_A, NNZ_C);
    for (int i = beg + threadIdx.x; i < end; i += 256)
        atomicAdd(&h[row[i] >> 8], 1);
    __syncthreads();
    for (int k = threadIdx.x; k < NBUCK2; k += 256) {
        int v = h[k];
        base[k] = v ? atomicAdd(&bcur[k], v) : 0;   // reserve private sub-range
    }
    __syncthreads();
    for (int k = threadIdx.x; k < NBUCK2; k += 256) h[k] = 0;  // reuse as local cursor
    __syncthreads();
    for (int i = beg + threadIdx.x; i < end; i += 256) {
        int r = row[i];
        int b = r >> 8;
        int ofs = atomicAdd(&h[b], 1);
        int pos = base[b] + ofs;
        tmp[pos] = make_int2(((r & 255) << 18) | col[i],   // lrow:8b | col:18b
                             __float_as_int(vals[i]));
    }
}

// ---------------- phase B: per-bucket counting sort -> final CSR + row_ptr ----------------
__global__ __launch_bounds__(256) void k_csr_build(const int* __restrict__ bbase,
                                                   const int2* __restrict__ tmp,
                                                   int2* __restrict__ edges,
                                                   int* __restrict__ row_ptr) {
    __shared__ int cnt[BROWS2];
    __shared__ int scn[BROWS2];
    __shared__ int cur[BROWS2];
    int b = blockIdx.x, t = threadIdx.x;
    int beg = bbase[b], end = bbase[b + 1];
    cnt[t] = 0;
    __syncthreads();
    for (int i = beg + t; i < end; i += 256)
        atomicAdd(&cnt[tmp[i].x >> 18], 1);
    __syncthreads();
    int v = cnt[t];
    scn[t] = v;
    __syncthreads();
    for (int off = 1; off < 256; off <<= 1) {
        int x = (t >= off) ? scn[t - off] : 0;
        __syncthreads();
        scn[t] += x;
        __syncthreads();
    }
    int excl = beg + scn[t] - v;
    cur[t] = excl;
    int g = b * BROWS2 + t;
    if (g < N_NODES) row_ptr[g] = excl;
    __syncthreads();
    for (int i = beg + t; i < end; i += 256) {
        int2 e = tmp[i];
        int pos = atomicAdd(&cur[e.x >> 18], 1);
        edges[pos] = make_int2(e.x & 0x3FFFF, e.y);
    }
}

// ---------------- SpMM: wave per row, lane = latent dim ----------------
template <bool SPLIT>
__global__ __launch_bounds__(256) void k_spmm(const int* __restrict__ row_ptr,
                                              const int2* __restrict__ edges,
                                              const float* __restrict__ x0,
                                              const float* __restrict__ x1,
                                              float* __restrict__ y) {
    int wv = (int)((blockIdx.x * blockDim.x + threadIdx.x) >> 6);
    int wave = __builtin_amdgcn_readfirstlane(wv);
    int lane = threadIdx.x & 63;
    if (wave >= N_NODES) return;
    int beg = row_ptr[wave], end = row_ptr[wave + 1];
    float a0 = 0.f, a1 = 0.f, a2 = 0.f, a3 = 0.f;
    auto xrow = [&](int c) -> const float* {
        if (SPLIT)
            return (c < N_USERS) ? x0 + ((size_t)c << 6)
                                 : x1 + ((size_t)(c - N_USERS) << 6);
        return x0 + ((size_t)c << 6);
    };
    int j = beg;
    for (; j + 4 <= end; j += 4) {
        int2 e0 = edges[j], e1 = edges[j + 1], e2 = edges[j + 2], e3 = edges[j + 3];
        a0 += __int_as_float(e0.y) * xrow(e0.x)[lane];
        a1 += __int_as_float(e1.y) * xrow(e1.x)[lane];
        a2 += __int_as_float(e2.y) * xrow(e2.x)[lane];
        a3 += __int_as_float(e3.y) * xrow(e3.x)[lane];
    }
    for (; j < end; ++j) {
        int2 e = edges[j];
        a0 += __int_as_float(e.y) * xrow(e.x)[lane];
    }
    y[((size_t)wave << 6) + lane] = (a0 + a1) + (a2 + a3);
}

// ---------------- partial SpMM over the 4096 selected rows: acc += (A·x)[sel] ----------------
__global__ __launch_bounds__(256) void k_spmm_sel(const int* __restrict__ row_ptr,
                                                  const int2* __restrict__ edges,
                                                  const float* __restrict__ x,
                                                  const int* __restrict__ users,
                                                  const int* __restrict__ items,
                                                  float* __restrict__ acc) {
    int w = (int)((blockIdx.x * blockDim.x + threadIdx.x) >> 6);
    int lane = threadIdx.x & 63;
    if (w >= 2 * BATCH) return;
    int node = (w < BATCH) ? users[w] : (N_USERS + items[w - BATCH]);
    node = __builtin_amdgcn_readfirstlane(node);
    int beg = row_ptr[node], end = row_ptr[node + 1];
    float a0 = 0.f, a1 = 0.f;
    int j = beg;
    for (; j + 2 <= end; j += 2) {
        int2 e0 = edges[j], e1 = edges[j + 1];
        a0 += __int_as_float(e0.y) * x[((size_t)e0.x << 6) + lane];
        a1 += __int_as_float(e1.y) * x[((size_t)e1.x << 6) + lane];
    }
    if (j < end) {
        int2 e = edges[j];
        a0 += __int_as_float(e.y) * x[((size_t)e.x << 6) + lane];
    }
    acc[w * LAT + lane] += a0 + a1;
}

// ---------------- selected-node accumulation ----------------
__global__ __launch_bounds__(256) void k_accsel_init(const float* __restrict__ U,
                                                     const float* __restrict__ I,
                                                     const int* __restrict__ users,
                                                     const int* __restrict__ items,
                                                     float* __restrict__ acc) {
    int gid = blockIdx.x * blockDim.x + threadIdx.x;
    int w = gid >> 6, lane = threadIdx.x & 63;
    if (w >= 2 * BATCH) return;
    const float* src = (w < BATCH) ? U + ((size_t)users[w] << 6)
                                   : I + ((size_t)items[w - BATCH] << 6);
    acc[w * LAT + lane] = src[lane];
}

__global__ __launch_bounds__(256) void k_accsel_add(const float* __restrict__ emb,
                                                    const int* __restrict__ users,
                                                    const int* __restrict__ items,
                                                    float* acc) {
    int gid = blockIdx.x * blockDim.x + threadIdx.x;
    int w = gid >> 6, lane = threadIdx.x & 63;
    if (w >= 2 * BATCH) return;
    int node = (w < BATCH) ? users[w] : (N_USERS + items[w - BATCH]);
    acc[w * LAT + lane] += emb[(size_t)node * LAT + lane];
}

__global__ __launch_bounds__(256) void k_dot(const float* __restrict__ acc,
                                             float* __restrict__ out) {
    int gid = blockIdx.x * blockDim.x + threadIdx.x;
    int w = gid >> 6, lane = threadIdx.x & 63;
    if (w >= BATCH) return;
    float p = acc[w * LAT + lane] * acc[(BATCH + w) * LAT + lane];
    for (int off = 32; off > 0; off >>= 1) p += __shfl_down(p, off, 64);
    if (lane == 0) out[w] = p * (1.0f / 16.0f);   // (/4)·(/4) folded in
}

// ---------------- launch ----------------
extern "C" void kernel_launch(void* const* d_in, const int* in_sizes, int n_in,
                              void* d_out, int out_size, void* d_ws, size_t ws_size,
                              hipStream_t stream) {
    const int*   row_idx  = (const int*)d_in[0];
    const int*   col_idx  = (const int*)d_in[1];
    const float* vals     = (const float*)d_in[2];
    const float* user_emb = (const float*)d_in[3];
    const float* item_emb = (const float*)d_in[4];
    const int*   users    = (const int*)d_in[5];
    const int*   items    = (const int*)d_in[6];
    float*       out      = (float*)d_out;

    char* ws = (char*)d_ws;
    size_t off = 0;
    auto alloc = [&](size_t bytes) -> void* {
        void* p = ws + off;
        off = (off + bytes + 255) & ~(size_t)255;
        return p;
    };
    int*   row_ptr = (int*)alloc((N_NODES + 1) * sizeof(int));
    int*   bcnt    = (int*)alloc(NBUCK2 * sizeof(int));
    int*   bbase   = (int*)alloc((NBUCK2 + 1) * sizeof(int));
    int*   bcur    = (int*)alloc(NBUCK2 * sizeof(int));
    int2*  edges   = (int2*)alloc((size_t)NNZ_C * sizeof(int2));
    float* embA    = (float*)alloc((size_t)N_NODES * LAT * sizeof(float));
    float* embB    = (float*)alloc((size_t)N_NODES * LAT * sizeof(float));
    float* acc     = (float*)alloc((size_t)2 * BATCH * LAT * sizeof(float));

    // tmp (48 MB AoS) aliases embA+embB (76.8 MB): fully consumed by k_csr_build
    // before any SpMM writes embA/embB.
    int2* tmp = (int2*)embA;

    // ---- CSR build (two-level LDS counting sort, no per-edge global atomics) ----
    k_zero<<<(NBUCK2 + 255) / 256, 256, 0, stream>>>(bcnt, NBUCK2);
    k_bucket_count<<<NBLK_A, 256, 0, stream>>>(row_idx, bcnt);
    k_bucket_scan<<<1, 256, 0, stream>>>(bcnt, bbase, bcur, row_ptr);
    k_bucket_scatter<<<NBLK_A, 256, 0, stream>>>(row_idx, col_idx, vals, bcur, tmp);
    k_csr_build<<<NBUCK2, 256, 0, stream>>>(bbase, tmp, edges, row_ptr);

    // ---- acc = e0[sel] ----
    k_accsel_init<<<(2 * BATCH * 64) / 256, 256, 0, stream>>>(user_emb, item_emb,
                                                              users, items, acc);

    // ---- B = A·e0 (full), acc += B[sel] ----
    k_spmm<true><<<(N_NODES + 3) / 4, 256, 0, stream>>>(row_ptr, edges,
                                                        user_emb, item_emb, embA);
    k_accsel_add<<<(2 * BATCH * 64) / 256, 256, 0, stream>>>(embA, users, items, acc);

    // ---- C = A·B (full), acc += C[sel] ----
    k_spmm<false><<<(N_NODES + 3) / 4, 256, 0, stream>>>(row_ptr, edges,
                                                         embA, nullptr, embB);
    k_accsel_add<<<(2 * BATCH * 64) / 256, 256, 0, stream>>>(embB, users, items, acc);

    // ---- acc += (A·C)[sel] — partial SpMM over 4096 selected rows only ----
    k_spmm_sel<<<(2 * BATCH * 64) / 256, 256, 0, stream>>>(row_ptr, edges, embB,
                                                           users, items, acc);

    // ---- gamma ----
    k_dot<<<(BATCH * 64) / 256, 256, 0, stream>>>(acc, out);
}